// Round 6
// baseline (1353.391 us; speedup 1.0000x reference)
//
#include <hip/hip_runtime.h>
#include <hip/hip_bf16.h>

#define NN 100000
#define EE 1000000
#define RR 10000
#define PP 50000

typedef _Float16 f16x8 __attribute__((ext_vector_type(8)));
typedef _Float16 f16x2 __attribute__((ext_vector_type(2)));
typedef float f32x4 __attribute__((ext_vector_type(4)));
typedef unsigned long long ull;

// ---------- helpers ----------
__device__ __forceinline__ float tfast(float x){
    float e = __expf(2.0f * x);
    return 1.0f - __fdividef(2.0f, e + 1.0f);
}
__device__ __forceinline__ unsigned encf(float f){
    unsigned u = __float_as_uint(f);
    return (u & 0x80000000u) ? ~u : (u | 0x80000000u);
}
__device__ __forceinline__ float decf(unsigned u){
    return (u & 0x80000000u) ? __uint_as_float(u ^ 0x80000000u) : __uint_as_float(~u);
}
__device__ __forceinline__ unsigned pk2(float a, float b){
    _Float16 ha = (_Float16)a, hb = (_Float16)b;
    unsigned short ua = __builtin_bit_cast(unsigned short, ha);
    unsigned short ub = __builtin_bit_cast(unsigned short, hb);
    return (unsigned)ua | ((unsigned)ub << 16);
}
__device__ __forceinline__ ull pk4(float a, float b, float c, float d){
    return ((ull)pk2(c, d) << 32) | (ull)pk2(a, b);
}

// ---------- xw1 = x @ W1[0:25,:] + b1  (per conv), stored f16 ----------
__global__ __launch_bounds__(256) void k_xw1(
    const float* __restrict__ x,
    const float* __restrict__ W1_0, const float* __restrict__ b1_0,
    const float* __restrict__ W1_1, const float* __restrict__ b1_1,
    const float* __restrict__ W1_2, const float* __restrict__ b1_2,
    _Float16* __restrict__ xw1)
{
    int g = blockIdx.x * 256 + threadIdx.x;          // 3*N*8 threads
    if (g >= 3 * NN * 8) return;
    int cv  = g / (NN * 8);
    int rem = g - cv * (NN * 8);
    int n   = rem >> 3, cg = rem & 7;
    const float* W1 = (cv == 0) ? W1_0 : ((cv == 1) ? W1_1 : W1_2);
    const float* b1 = (cv == 0) ? b1_0 : ((cv == 1) ? b1_1 : b1_2);
    float4 acc = *(const float4*)&b1[cg * 4];
    const float* xr = x + (size_t)n * 25;
    #pragma unroll
    for (int m = 0; m < 25; m++){
        float xv = xr[m];
        float4 w = *(const float4*)&W1[m * 32 + cg * 4];
        acc.x = fmaf(xv, w.x, acc.x); acc.y = fmaf(xv, w.y, acc.y);
        acc.z = fmaf(xv, w.z, acc.z); acc.w = fmaf(xv, w.w, acc.w);
    }
    *(ull*)&xw1[((size_t)cv * NN + n) * 32 + cg * 4] = pk4(acc.x, acc.y, acc.z, acc.w);
}

// ---------- Wa -> fragment-linear f16 table BF ----------
__global__ __launch_bounds__(256) void k_prep(const float* __restrict__ Wa, _Float16* __restrict__ BF)
{
    int g = blockIdx.x * 256 + threadIdx.x;     // 96 blocks
    int o = g * 4;
    int j0 = o & 7;
    int t1 = o >> 3;
    int ln = t1 & 15;
    int t2 = t1 >> 4;
    int kg = t2 & 3;
    int t3 = t2 >> 2;
    int c  = t3 % 12;
    int nt = t3 / 12;
    int colg = nt * 16 + ln;
    int krow = c * 32 + kg * 8 + j0;
    float w0 = Wa[(size_t)(krow + 0) * 256 + colg];
    float w1 = Wa[(size_t)(krow + 1) * 256 + colg];
    float w2 = Wa[(size_t)(krow + 2) * 256 + colg];
    float w3 = Wa[(size_t)(krow + 3) * 256 + colg];
    *(ull*)&BF[o] = pk4(w0, w1, w2, w3);
}

// ---------- W2 -> fragment-linear f16 tables (3 convs) ----------
__global__ __launch_bounds__(256) void k_prepw(
    const float* __restrict__ W2_0, const float* __restrict__ W2_1, const float* __restrict__ W2_2,
    _Float16* __restrict__ W2F)
{
    int g = blockIdx.x * 256 + threadIdx.x;     // 6 blocks -> 1536 threads
    int cv = g >> 9;
    int f  = g & 511;
    int ln = f & 15;
    int kg = (f >> 4) & 3;
    int mt = f >> 6;
    const float* W2 = (cv == 0) ? W2_0 : ((cv == 1) ? W2_1 : W2_2);
    f16x8 v;
    #pragma unroll
    for (int jj = 0; jj < 8; jj++)
        v[jj] = (_Float16)W2[(kg * 8 + jj) * 128 + mt * 16 + ln];
    ((f16x8*)W2F)[g] = v;
}

// ---------- histogram of edge targets ----------
__global__ __launch_bounds__(256) void k_hist(
    const int* __restrict__ e2, const int* __restrict__ e3, const int* __restrict__ e4,
    unsigned* __restrict__ cur)
{
    long g = (long)blockIdx.x * 256 + threadIdx.x;
    if (g >= 3L * EE) return;
    int cv = (int)(g / EE);
    int e  = (int)(g - (long)cv * EE);
    const int* ei = (cv == 0) ? e2 : ((cv == 1) ? e3 : e4);
    int tg = ei[EE + e];
    atomicAdd(&cur[cv * NN + tg], 1u);
}

// ---------- in-place exclusive scan (3 blocks, one per conv) ----------
__global__ __launch_bounds__(1024) void k_scan(unsigned* __restrict__ cur)
{
    int cv = blockIdx.x;
    unsigned* a = cur + (size_t)cv * NN;
    __shared__ unsigned wsum[16];
    __shared__ unsigned carry;
    if (threadIdx.x == 0) carry = 0;
    int lane = threadIdx.x & 63, wv = threadIdx.x >> 6;
    for (int base = 0; base < NN; base += 1024){
        int idx = base + threadIdx.x;
        unsigned v = (idx < NN) ? a[idx] : 0u;
        unsigned s = v;
        #pragma unroll
        for (int d = 1; d < 64; d <<= 1){
            unsigned t = (unsigned)__shfl_up((int)s, d);
            if (lane >= d) s += t;
        }
        if (lane == 63) wsum[wv] = s;
        __syncthreads();
        if (wv == 0 && lane < 16){
            unsigned t = wsum[lane];
            #pragma unroll
            for (int d = 1; d < 16; d <<= 1){
                unsigned u = (unsigned)__shfl_up((int)t, d);
                if (lane >= d) t += u;
            }
            wsum[lane] = t;
        }
        __syncthreads();
        unsigned waveoff = (wv == 0) ? 0u : wsum[wv - 1];
        unsigned excl = carry + waveoff + s - v;
        if (idx < NN) a[idx] = excl;
        __syncthreads();
        if (threadIdx.x == 0) carry += wsum[15];
        __syncthreads();
    }
}

// ---------- scatter edges into target-sorted order (packed tgt|src) ----------
__global__ __launch_bounds__(256) void k_scatter(
    const int* __restrict__ e2, const int* __restrict__ e3, const int* __restrict__ e4,
    unsigned* __restrict__ cur, ull* __restrict__ esort)
{
    long g = (long)blockIdx.x * 256 + threadIdx.x;
    if (g >= 3L * EE) return;
    int cv = (int)(g / EE);
    int e  = (int)(g - (long)cv * EE);
    const int* ei = (cv == 0) ? e2 : ((cv == 1) ? e3 : e4);
    int j  = ei[e];
    int tg = ei[EE + e];
    unsigned p = atomicAdd(&cur[cv * NN + tg], 1u);
    esort[(size_t)cv * EE + p] = ((ull)(unsigned)tg << 32) | (unsigned)j;
}

// ---------- fused PPF conv ----------
__global__ __launch_bounds__(256) void k_conv(
    const ull* __restrict__ esort,
    const _Float16* __restrict__ xw1,
    const float* __restrict__ pos, const float* __restrict__ nrm,
    const float* __restrict__ W1_0, const float* __restrict__ W1_1, const float* __restrict__ W1_2,
    const _Float16* __restrict__ W2F,
    const float* __restrict__ b2_0, const float* __restrict__ b2_1, const float* __restrict__ b2_2,
    unsigned* __restrict__ feat)
{
    const int cv = blockIdx.y;
    const float invR = (cv == 0) ? 0.2f : ((cv == 1) ? (1.0f / 8.5f) : 0.1f);
    const float* W1 = (cv == 0) ? W1_0 : ((cv == 1) ? W1_1 : W1_2);
    const float* b2 = (cv == 0) ? b2_0 : ((cv == 1) ? b2_1 : b2_2);
    const ull* eS = esort + (size_t)cv * EE;
    const _Float16* xw = xw1 + (size_t)cv * NN * 32;

    __shared__ __align__(16) _Float16 hS[128 * 32];
    __shared__ __align__(16) _Float16 sLds[128 * 128];
    __shared__ float w1p[224];
    __shared__ int tgtL[128];

    int tid = threadIdx.x;
    if (tid < 224) w1p[tid] = W1[800 + tid];

    int gbase = blockIdx.x * 128;
    int e     = tid & 127;
    int hlf   = tid >> 7;
    int eg = gbase + e; if (eg >= EE) eg = EE - 1;
    ull ev = eS[eg];
    int j  = (int)(unsigned)(ev & 0xffffffffu);
    int it = (int)(unsigned)(ev >> 32);
    if (hlf == 0) tgtL[e] = it;
    __syncthreads();

    float pix = pos[(size_t)it * 3 + 0], piy = pos[(size_t)it * 3 + 1], piz = pos[(size_t)it * 3 + 2];
    float pjx = pos[(size_t)j  * 3 + 0], pjy = pos[(size_t)j  * 3 + 1], pjz = pos[(size_t)j  * 3 + 2];
    float nix = nrm[(size_t)it * 3 + 0], niy = nrm[(size_t)it * 3 + 1], niz = nrm[(size_t)it * 3 + 2];
    float njx = nrm[(size_t)j  * 3 + 0], njy = nrm[(size_t)j  * 3 + 1], njz = nrm[(size_t)j  * 3 + 2];

    float dx = pjx - pix, dy = pjy - piy, dz = pjz - piz;
    float dist = sqrtf(dx * dx + dy * dy + dz * dz + 1e-12f);

    float cx = niy * dz - niz * dy, cyv = niz * dx - nix * dz, cz = nix * dy - niy * dx;
    float y1 = sqrtf(cx * cx + cyv * cyv + cz * cz + 1e-12f);
    float x1 = nix * dx + niy * dy + niz * dz;
    float ir = __frsqrt_rn(x1 * x1 + y1 * y1);
    float s1 = y1 * ir, c1 = x1 * ir;
    cx = njy * dz - njz * dy; cyv = njz * dx - njx * dz; cz = njx * dy - njy * dx;
    float y2 = sqrtf(cx * cx + cyv * cyv + cz * cz + 1e-12f);
    float x2 = njx * dx + njy * dy + njz * dz;
    ir = __frsqrt_rn(x2 * x2 + y2 * y2);
    float s2 = y2 * ir, c2 = x2 * ir;
    cx = niy * njz - niz * njy; cyv = niz * njx - nix * njz; cz = nix * njy - niy * njx;
    float y3 = sqrtf(cx * cx + cyv * cyv + cz * cz + 1e-12f);
    float x3 = nix * njx + niy * njy + niz * njz;
    ir = __frsqrt_rn(x3 * x3 + y3 * y3);
    float s3 = y3 * ir, c3 = x3 * ir;

    float ppf[7] = { dist * invR, s1, c1, s2, c2, s3, c3 };

    int ch0 = hlf * 16;
    float h16[16];
    {
        const f16x8* xr = (const f16x8*)(xw + (size_t)j * 32 + ch0);
        f16x8 v0 = xr[0], v1 = xr[1];
        #pragma unroll
        for (int q = 0; q < 8; q++){ h16[q] = (float)v0[q]; h16[8 + q] = (float)v1[q]; }
    }
    #pragma unroll
    for (int f = 0; f < 7; f++){
        float pv = ppf[f];
        const float4* w4 = (const float4*)&w1p[f * 32 + ch0];
        #pragma unroll
        for (int q = 0; q < 4; q++){
            float4 w = w4[q];
            h16[q*4+0] = fmaf(pv, w.x, h16[q*4+0]);
            h16[q*4+1] = fmaf(pv, w.y, h16[q*4+1]);
            h16[q*4+2] = fmaf(pv, w.z, h16[q*4+2]);
            h16[q*4+3] = fmaf(pv, w.w, h16[q*4+3]);
        }
    }
    #pragma unroll
    for (int c = 0; c < 16; c++) h16[c] = tfast(h16[c]);

    {
        f16x8 c0v, c1v;
        #pragma unroll
        for (int q = 0; q < 8; q++){ c0v[q] = (_Float16)h16[q]; c1v[q] = (_Float16)h16[8 + q]; }
        int key = (e >> 1) & 3;
        int kg0 = 2 * hlf;
        *(f16x8*)&hS[e * 32 + ((kg0     ) ^ key) * 8] = c0v;
        *(f16x8*)&hS[e * 32 + ((kg0 + 1) ^ key) * 8] = c1v;
    }
    __syncthreads();

    // ---- phase B: s = h @ W2 via f16 MFMA, A-frags from precomputed W2F ----
    int lane = tid & 63, wv = tid >> 6;
    int ln15 = lane & 15, kg = lane >> 4;
    const f16x8* w2f = (const f16x8*)W2F + (size_t)cv * 512;
    f16x8 a[8];
    #pragma unroll
    for (int mt = 0; mt < 8; mt++)
        a[mt] = w2f[(mt * 4 + kg) * 16 + ln15];

    f32x4 acc[2][8];
    #pragma unroll
    for (int n = 0; n < 2; n++)
        #pragma unroll
        for (int mt = 0; mt < 8; mt++)
            acc[n][mt] = (f32x4){0.f, 0.f, 0.f, 0.f};

    #pragma unroll
    for (int nti = 0; nti < 2; nti++){
        int ee = (2 * wv + nti) * 16 + ln15;
        f16x8 b = *(const f16x8*)&hS[ee * 32 + (kg ^ ((ee >> 1) & 3)) * 8];
        #pragma unroll
        for (int mt = 0; mt < 8; mt++)
            acc[nti][mt] = __builtin_amdgcn_mfma_f32_16x16x32_f16(a[mt], b, acc[nti][mt], 0, 0, 0);
    }
    #pragma unroll
    for (int nti = 0; nti < 2; nti++){
        int ee  = (2 * wv + nti) * 16 + ln15;
        int key = ee & 15;
        #pragma unroll
        for (int mt = 0; mt < 8; mt++){
            unsigned lo = pk2(acc[nti][mt][0], acc[nti][mt][1]);
            unsigned hi = pk2(acc[nti][mt][2], acc[nti][mt][3]);
            int u = mt * 4 + kg;
            ull v = ((ull)hi << 32) | lo;
            *(ull*)&sLds[ee * 128 + ((u ^ key) << 2)] = v;
        }
    }
    __syncthreads();

    // ---- phase C: packed-f16 segmented max, 4 channels/thread, 16 edges/group ----
    int egp = tid >> 5;          // 0..7 edge group (16 edges)
    int cg  = tid & 31;          // channel group (4 channels)
    float4 b2v = *(const float4*)&b2[cg * 4];
    int curT = -1;
    f16x2 m01 = (f16x2)(_Float16)(-60000.0f), m23 = m01;
    int ebase = egp * 16;
    #pragma unroll
    for (int er = 0; er < 16; er++){
        int ee = ebase + er;
        int tg = tgtL[ee];
        ull sv = *(const ull*)&sLds[ee * 128 + ((cg ^ er) << 2)];
        f16x2 s01 = __builtin_bit_cast(f16x2, (unsigned)(sv & 0xffffffffu));
        f16x2 s23 = __builtin_bit_cast(f16x2, (unsigned)(sv >> 32));
        if (tg != curT){
            if (curT >= 0){
                unsigned* fp = &feat[(size_t)curT * 384 + cv * 128 + cg * 4];
                atomicMax(fp + 0, encf((float)m01[0] + b2v.x));
                atomicMax(fp + 1, encf((float)m01[1] + b2v.y));
                atomicMax(fp + 2, encf((float)m23[0] + b2v.z));
                atomicMax(fp + 3, encf((float)m23[1] + b2v.w));
            }
            curT = tg; m01 = s01; m23 = s23;
        } else {
            m01 = __builtin_elementwise_max(m01, s01);
            m23 = __builtin_elementwise_max(m23, s23);
        }
    }
    {
        unsigned* fp = &feat[(size_t)curT * 384 + cv * 128 + cg * 4];
        atomicMax(fp + 0, encf((float)m01[0] + b2v.x));
        atomicMax(fp + 1, encf((float)m01[1] + b2v.y));
        atomicMax(fp + 2, encf((float)m23[0] + b2v.z));
        atomicMax(fp + 3, encf((float)m23[1] + b2v.w));
    }
}

// ---------- atom MLP via MFMA + residue max-pool (no atomics) ----------
__global__ __launch_bounds__(256) void k_atom(
    const unsigned* __restrict__ feat, const _Float16* __restrict__ BF,
    const float* __restrict__ ba, float* __restrict__ resm)
{
    __shared__ __align__(16) char ldsbuf[81920];
    _Float16* Ah = (_Float16*)ldsbuf;
    float*    Cs = (float*)ldsbuf;

    int tid = threadIdx.x;
    size_t base = (size_t)blockIdx.x * 80 * 384;

    #pragma unroll
    for (int itr = 0; itr < 30; itr++){
        int idx = itr * 1024 + tid * 4;
        uint4 v = *(const uint4*)&feat[base + idx];
        int r = idx / 384;
        int k = idx - r * 384;
        float f0 = tfast(decf(v.x));
        float f1 = tfast(decf(v.y));
        float f2 = tfast(decf(v.z));
        float f3 = tfast(decf(v.w));
        int u = (k >> 3) ^ (r & 7);
        *(ull*)&Ah[r * 384 + u * 8 + (k & 7)] = pk4(f0, f1, f2, f3);
    }
    __syncthreads();

    int lane = tid & 63, wv = tid >> 6;
    int ln15 = lane & 15, kg = lane >> 4;
    f32x4 acc[5][4];
    #pragma unroll
    for (int mt = 0; mt < 5; mt++)
        #pragma unroll
        for (int nti = 0; nti < 4; nti++)
            acc[mt][nti] = (f32x4){0.f, 0.f, 0.f, 0.f};

    const f16x8* bfp = (const f16x8*)BF;
    #pragma unroll
    for (int c = 0; c < 12; c++){
        f16x8 af[5];
        #pragma unroll
        for (int mt = 0; mt < 5; mt++){
            int row = mt * 16 + ln15;
            af[mt] = *(const f16x8*)&Ah[row * 384 + (((c * 4 + kg) ^ (row & 7)) << 3)];
        }
        #pragma unroll
        for (int nti = 0; nti < 4; nti++){
            f16x8 b = bfp[(((wv * 4 + nti) * 12 + c) * 4 + kg) * 16 + ln15];
            #pragma unroll
            for (int mt = 0; mt < 5; mt++)
                acc[mt][nti] = __builtin_amdgcn_mfma_f32_16x16x32_f16(af[mt], b, acc[mt][nti], 0, 0, 0);
        }
    }
    __syncthreads();

    #pragma unroll
    for (int nti = 0; nti < 4; nti++){
        int col = wv * 64 + nti * 16 + ln15;
        float bac = ba[col];
        #pragma unroll
        for (int mt = 0; mt < 5; mt++){
            #pragma unroll
            for (int q = 0; q < 4; q++){
                int row = mt * 16 + kg * 4 + q;
                Cs[row * 256 + (col ^ (kg << 2))] = acc[mt][nti][q] + bac;
            }
        }
    }
    __syncthreads();

    int res0 = blockIdx.x * 8;
    #pragma unroll
    for (int o = 0; o < 8; o++){
        int out = o * 256 + tid;
        int r = out >> 8, cc = out & 255;
        float m = -3.0e38f;
        #pragma unroll
        for (int q = 0; q < 10; q++){
            int row = r * 10 + q;
            m = fmaxf(m, Cs[row * 256 + (cc ^ (((row >> 2) & 3) << 2))]);
        }
        resm[(size_t)(res0 + r) * 256 + cc] = tfast(m);
    }
}

// ---------- res MLP + fused lw = tanh(resm@Wr+br) @ Wl ----------
__global__ __launch_bounds__(256) void k_res(
    const float* __restrict__ resm, const float* __restrict__ Wr,
    const float* __restrict__ br, const float* __restrict__ Wl,
    float* __restrict__ lw)
{
    __shared__ __align__(16) float As[16 * 16];
    __shared__ __align__(16) float Ws[16 * 512];
    __shared__ float lwL[16];
    int tid  = threadIdx.x;
    int row0 = blockIdx.x * 16;
    int colg = tid & 127, rowg = tid >> 7;
    int c0 = colg * 4;
    int lane = tid & 63;
    if (tid < 16) lwL[tid] = 0.0f;
    float4 acc[8];
    float4 brv = *(const float4*)&br[c0];
    #pragma unroll
    for (int r = 0; r < 8; r++) acc[r] = brv;

    for (int k0 = 0; k0 < 256; k0 += 16){
        __syncthreads();
        { int r = tid >> 4, k = tid & 15;
          As[tid] = resm[(size_t)(row0 + r) * 256 + k0 + k]; }
        #pragma unroll
        for (int t0 = 0; t0 < 32; t0++){
            int t = tid + t0 * 256;
            int k = t >> 9, c = t & 511;
            Ws[t] = Wr[(size_t)(k0 + k) * 512 + c];
        }
        __syncthreads();
        #pragma unroll
        for (int kk = 0; kk < 16; kk += 4){
            float4 w0 = *(const float4*)&Ws[(kk + 0) * 512 + c0];
            float4 w1 = *(const float4*)&Ws[(kk + 1) * 512 + c0];
            float4 w2 = *(const float4*)&Ws[(kk + 2) * 512 + c0];
            float4 w3 = *(const float4*)&Ws[(kk + 3) * 512 + c0];
            #pragma unroll
            for (int r = 0; r < 8; r++){
                const float4 a = *(const float4*)&As[(rowg * 8 + r) * 16 + kk];
                acc[r].x = fmaf(a.x, w0.x, fmaf(a.y, w1.x, fmaf(a.z, w2.x, fmaf(a.w, w3.x, acc[r].x))));
                acc[r].y = fmaf(a.x, w0.y, fmaf(a.y, w1.y, fmaf(a.z, w2.y, fmaf(a.w, w3.y, acc[r].y))));
                acc[r].z = fmaf(a.x, w0.z, fmaf(a.y, w1.z, fmaf(a.z, w2.z, fmaf(a.w, w3.z, acc[r].z))));
                acc[r].w = fmaf(a.x, w0.w, fmaf(a.y, w1.w, fmaf(a.z, w2.w, fmaf(a.w, w3.w, acc[r].w))));
            }
        }
    }
    float4 wl = *(const float4*)&Wl[c0];
    #pragma unroll
    for (int r = 0; r < 8; r++){
        float4 v = acc[r];
        float p = tfast(v.x) * wl.x + tfast(v.y) * wl.y + tfast(v.z) * wl.z + tfast(v.w) * wl.w;
        #pragma unroll
        for (int m = 1; m < 64; m <<= 1) p += __shfl_xor(p, m);
        if (lane == 0) atomicAdd(&lwL[rowg * 8 + r], p);
    }
    __syncthreads();
    if (tid < 16) lw[row0 + tid] = lwL[tid];
}

// ---------- final pair logits ----------
__global__ __launch_bounds__(256) void k_out(
    const float* __restrict__ lw, const int* __restrict__ src, const int* __restrict__ tgt,
    const float* __restrict__ bl, float* __restrict__ out)
{
    int p = blockIdx.x * 256 + threadIdx.x;
    if (p < PP) out[p] = lw[src[p]] - lw[tgt[p]] + bl[0];
}

extern "C" void kernel_launch(void* const* d_in, const int* in_sizes, int n_in,
                              void* d_out, int out_size, void* d_ws, size_t ws_size,
                              hipStream_t stream)
{
    const float* x    = (const float*)d_in[0];
    const float* pos  = (const float*)d_in[1];
    const float* nrm  = (const float*)d_in[2];
    const int*   ei2  = (const int*)d_in[3];
    const int*   ei3  = (const int*)d_in[4];
    const int*   ei4  = (const int*)d_in[5];
    const int*   srci = (const int*)d_in[7];
    const int*   tgti = (const int*)d_in[8];
    const float* c2W1 = (const float*)d_in[9];
    const float* c2b1 = (const float*)d_in[10];
    const float* c2W2 = (const float*)d_in[11];
    const float* c2b2 = (const float*)d_in[12];
    const float* c3W1 = (const float*)d_in[13];
    const float* c3b1 = (const float*)d_in[14];
    const float* c3W2 = (const float*)d_in[15];
    const float* c3b2 = (const float*)d_in[16];
    const float* c4W1 = (const float*)d_in[17];
    const float* c4b1 = (const float*)d_in[18];
    const float* c4W2 = (const float*)d_in[19];
    const float* c4b2 = (const float*)d_in[20];
    const float* Wa   = (const float*)d_in[21];
    const float* ba   = (const float*)d_in[22];
    const float* Wr   = (const float*)d_in[23];
    const float* br   = (const float*)d_in[24];
    const float* Wl   = (const float*)d_in[25];
    const float* bl   = (const float*)d_in[26];

    char* ws = (char*)d_ws;
    _Float16* xw1  = (_Float16*)(ws);                 // 19,200,000 B
    _Float16* W2F  = (_Float16*)(ws +  19200000);     //     24,576 B
    _Float16* BF   = (_Float16*)(ws +  19224576);     //    196,608 B
    unsigned* cur  = (unsigned*)(ws +  19421184);     //  1,200,000 B
    ull*      esort= (ull*)     (ws +  20621312);     // 24,000,000 B
    unsigned* feat = (unsigned*)(ws +  44621312);     // 153,600,000 B
    float*    resm = (float*)   (ws + 198221312);     // 10,240,000 B
    float*    lw   = (float*)   (ws + 208461312);     // 40,000 B

    hipMemsetAsync(cur,  0, (size_t)3 * NN * 4, stream);
    hipMemsetAsync(feat, 0, (size_t)NN * 384 * 4, stream);

    k_xw1<<<9375, 256, 0, stream>>>(x, c2W1, c2b1, c3W1, c3b1, c4W1, c4b1, xw1);
    k_prep<<<96, 256, 0, stream>>>(Wa, BF);
    k_prepw<<<6, 256, 0, stream>>>(c2W2, c3W2, c4W2, W2F);
    k_hist<<<(3 * EE + 255) / 256, 256, 0, stream>>>(ei2, ei3, ei4, cur);
    k_scan<<<3, 1024, 0, stream>>>(cur);
    k_scatter<<<(3 * EE + 255) / 256, 256, 0, stream>>>(ei2, ei3, ei4, cur, esort);
    dim3 gconv((EE + 127) / 128, 3);
    k_conv<<<gconv, 256, 0, stream>>>(esort, xw1, pos, nrm,
                                      c2W1, c3W1, c4W1, W2F,
                                      c2b2, c3b2, c4b2, feat);
    k_atom<<<NN / 80, 256, 0, stream>>>(feat, BF, ba, resm);
    k_res<<<RR / 16, 256, 0, stream>>>(resm, Wr, br, Wl, lw);
    k_out<<<(PP + 255) / 256, 256, 0, stream>>>(lw, srci, tgti, bl, (float*)d_out);
}

// Round 9
// 950.930 us; speedup vs baseline: 1.4232x; 1.4232x over previous
//
#include <hip/hip_runtime.h>
#include <hip/hip_bf16.h>

#define NN 100000
#define EE 1000000
#define RR 10000
#define PP 50000

typedef _Float16 f16x8 __attribute__((ext_vector_type(8)));
typedef _Float16 f16x2 __attribute__((ext_vector_type(2)));
typedef float f32x4 __attribute__((ext_vector_type(4)));
typedef unsigned long long ull;

// ---------- helpers ----------
__device__ __forceinline__ float tfast(float x){
    float e = __expf(2.0f * x);
    return 1.0f - __fdividef(2.0f, e + 1.0f);
}
__device__ __forceinline__ unsigned encf(float f){
    unsigned u = __float_as_uint(f);
    return (u & 0x80000000u) ? ~u : (u | 0x80000000u);
}
__device__ __forceinline__ float decf(unsigned u){
    return (u & 0x80000000u) ? __uint_as_float(u ^ 0x80000000u) : __uint_as_float(~u);
}
__device__ __forceinline__ unsigned pk2(float a, float b){
    _Float16 ha = (_Float16)a, hb = (_Float16)b;
    unsigned short ua = __builtin_bit_cast(unsigned short, ha);
    unsigned short ub = __builtin_bit_cast(unsigned short, hb);
    return (unsigned)ua | ((unsigned)ub << 16);
}
__device__ __forceinline__ ull pk4(float a, float b, float c, float d){
    return ((ull)pk2(c, d) << 32) | (ull)pk2(a, b);
}

// ---------- xw1 = x @ W1[0:25,:] + b1  (per conv), stored f16 ----------
__global__ __launch_bounds__(256) void k_xw1(
    const float* __restrict__ x,
    const float* __restrict__ W1_0, const float* __restrict__ b1_0,
    const float* __restrict__ W1_1, const float* __restrict__ b1_1,
    const float* __restrict__ W1_2, const float* __restrict__ b1_2,
    _Float16* __restrict__ xw1)
{
    int g = blockIdx.x * 256 + threadIdx.x;          // 3*N*8 threads
    if (g >= 3 * NN * 8) return;
    int cv  = g / (NN * 8);
    int rem = g - cv * (NN * 8);
    int n   = rem >> 3, cg = rem & 7;
    const float* W1 = (cv == 0) ? W1_0 : ((cv == 1) ? W1_1 : W1_2);
    const float* b1 = (cv == 0) ? b1_0 : ((cv == 1) ? b1_1 : b1_2);
    float4 acc = *(const float4*)&b1[cg * 4];
    const float* xr = x + (size_t)n * 25;
    #pragma unroll
    for (int m = 0; m < 25; m++){
        float xv = xr[m];
        float4 w = *(const float4*)&W1[m * 32 + cg * 4];
        acc.x = fmaf(xv, w.x, acc.x); acc.y = fmaf(xv, w.y, acc.y);
        acc.z = fmaf(xv, w.z, acc.z); acc.w = fmaf(xv, w.w, acc.w);
    }
    *(ull*)&xw1[((size_t)cv * NN + n) * 32 + cg * 4] = pk4(acc.x, acc.y, acc.z, acc.w);
}

// ---------- Wa -> fragment-linear f16 table BF ----------
__global__ __launch_bounds__(256) void k_prep(const float* __restrict__ Wa, _Float16* __restrict__ BF)
{
    int g = blockIdx.x * 256 + threadIdx.x;     // 96 blocks
    int o = g * 4;
    int j0 = o & 7;
    int t1 = o >> 3;
    int ln = t1 & 15;
    int t2 = t1 >> 4;
    int kg = t2 & 3;
    int t3 = t2 >> 2;
    int c  = t3 % 12;
    int nt = t3 / 12;
    int colg = nt * 16 + ln;
    int krow = c * 32 + kg * 8 + j0;
    float w0 = Wa[(size_t)(krow + 0) * 256 + colg];
    float w1 = Wa[(size_t)(krow + 1) * 256 + colg];
    float w2 = Wa[(size_t)(krow + 2) * 256 + colg];
    float w3 = Wa[(size_t)(krow + 3) * 256 + colg];
    *(ull*)&BF[o] = pk4(w0, w1, w2, w3);
}

// ---------- W2 -> fragment-linear f16 tables (3 convs) ----------
__global__ __launch_bounds__(256) void k_prepw(
    const float* __restrict__ W2_0, const float* __restrict__ W2_1, const float* __restrict__ W2_2,
    _Float16* __restrict__ W2F)
{
    int g = blockIdx.x * 256 + threadIdx.x;     // 6 blocks -> 1536 threads
    int cv = g >> 9;
    int f  = g & 511;
    int ln = f & 15;
    int kg = (f >> 4) & 3;
    int mt = f >> 6;
    const float* W2 = (cv == 0) ? W2_0 : ((cv == 1) ? W2_1 : W2_2);
    f16x8 v;
    #pragma unroll
    for (int jj = 0; jj < 8; jj++)
        v[jj] = (_Float16)W2[(kg * 8 + jj) * 128 + mt * 16 + ln];
    ((f16x8*)W2F)[g] = v;
}

// ---------- histogram of edge targets ----------
__global__ __launch_bounds__(256) void k_hist(
    const int* __restrict__ e2, const int* __restrict__ e3, const int* __restrict__ e4,
    unsigned* __restrict__ cur)
{
    long g = (long)blockIdx.x * 256 + threadIdx.x;
    if (g >= 3L * EE) return;
    int cv = (int)(g / EE);
    int e  = (int)(g - (long)cv * EE);
    const int* ei = (cv == 0) ? e2 : ((cv == 1) ? e3 : e4);
    int tg = ei[EE + e];
    atomicAdd(&cur[cv * NN + tg], 1u);
}

// ---------- in-place exclusive scan (3 blocks, one per conv) ----------
__global__ __launch_bounds__(1024) void k_scan(unsigned* __restrict__ cur)
{
    int cv = blockIdx.x;
    unsigned* a = cur + (size_t)cv * NN;
    __shared__ unsigned wsum[16];
    __shared__ unsigned carry;
    if (threadIdx.x == 0) carry = 0;
    int lane = threadIdx.x & 63, wv = threadIdx.x >> 6;
    for (int base = 0; base < NN; base += 1024){
        int idx = base + threadIdx.x;
        unsigned v = (idx < NN) ? a[idx] : 0u;
        unsigned s = v;
        #pragma unroll
        for (int d = 1; d < 64; d <<= 1){
            unsigned t = (unsigned)__shfl_up((int)s, d);
            if (lane >= d) s += t;
        }
        if (lane == 63) wsum[wv] = s;
        __syncthreads();
        if (wv == 0 && lane < 16){
            unsigned t = wsum[lane];
            #pragma unroll
            for (int d = 1; d < 16; d <<= 1){
                unsigned u = (unsigned)__shfl_up((int)t, d);
                if (lane >= d) t += u;
            }
            wsum[lane] = t;
        }
        __syncthreads();
        unsigned waveoff = (wv == 0) ? 0u : wsum[wv - 1];
        unsigned excl = carry + waveoff + s - v;
        if (idx < NN) a[idx] = excl;
        __syncthreads();
        if (threadIdx.x == 0) carry += wsum[15];
        __syncthreads();
    }
}

// ---------- scatter edges into target-sorted order (packed tgt|src) ----------
__global__ __launch_bounds__(256) void k_scatter(
    const int* __restrict__ e2, const int* __restrict__ e3, const int* __restrict__ e4,
    unsigned* __restrict__ cur, ull* __restrict__ esort)
{
    long g = (long)blockIdx.x * 256 + threadIdx.x;
    if (g >= 3L * EE) return;
    int cv = (int)(g / EE);
    int e  = (int)(g - (long)cv * EE);
    const int* ei = (cv == 0) ? e2 : ((cv == 1) ? e3 : e4);
    int j  = ei[e];
    int tg = ei[EE + e];
    unsigned p = atomicAdd(&cur[cv * NN + tg], 1u);
    esort[(size_t)cv * EE + p] = ((ull)(unsigned)tg << 32) | (unsigned)j;
}

// ---------- fused PPF conv ----------
// sLds channel permutation: 8B unit u (u=0..31) holds channels {u, u+32, u+64, u+96}
// (slot = ch>>5). Phase-C thread u owns those 4 channels; flush instruction k writes
// feat word k*32+u -> 32 lanes contiguous 128B per atomic instruction (coalesced).
__global__ __launch_bounds__(256) void k_conv(
    const ull* __restrict__ esort,
    const _Float16* __restrict__ xw1,
    const float* __restrict__ pos, const float* __restrict__ nrm,
    const float* __restrict__ W1_0, const float* __restrict__ W1_1, const float* __restrict__ W1_2,
    const _Float16* __restrict__ W2F,
    const float* __restrict__ b2_0, const float* __restrict__ b2_1, const float* __restrict__ b2_2,
    unsigned* __restrict__ feat)
{
    const int cv = blockIdx.y;
    const float invR = (cv == 0) ? 0.2f : ((cv == 1) ? (1.0f / 8.5f) : 0.1f);
    const float* W1 = (cv == 0) ? W1_0 : ((cv == 1) ? W1_1 : W1_2);
    const float* b2 = (cv == 0) ? b2_0 : ((cv == 1) ? b2_1 : b2_2);
    const ull* eS = esort + (size_t)cv * EE;
    const _Float16* xw = xw1 + (size_t)cv * NN * 32;

    __shared__ __align__(16) _Float16 hS[128 * 32];
    __shared__ __align__(16) _Float16 sLds[128 * 128];
    __shared__ float w1p[224];
    __shared__ int tgtL[128];

    int tid = threadIdx.x;
    if (tid < 224) w1p[tid] = W1[800 + tid];

    int gbase = blockIdx.x * 128;
    int e     = tid & 127;
    int hlf   = tid >> 7;
    int eg = gbase + e; if (eg >= EE) eg = EE - 1;   // dup last edge: max-idempotent
    ull ev = eS[eg];
    int j  = (int)(unsigned)(ev & 0xffffffffu);
    int it = (int)(unsigned)(ev >> 32);
    if (hlf == 0) tgtL[e] = it;
    __syncthreads();

    float pix = pos[(size_t)it * 3 + 0], piy = pos[(size_t)it * 3 + 1], piz = pos[(size_t)it * 3 + 2];
    float pjx = pos[(size_t)j  * 3 + 0], pjy = pos[(size_t)j  * 3 + 1], pjz = pos[(size_t)j  * 3 + 2];
    float nix = nrm[(size_t)it * 3 + 0], niy = nrm[(size_t)it * 3 + 1], niz = nrm[(size_t)it * 3 + 2];
    float njx = nrm[(size_t)j  * 3 + 0], njy = nrm[(size_t)j  * 3 + 1], njz = nrm[(size_t)j  * 3 + 2];

    float dx = pjx - pix, dy = pjy - piy, dz = pjz - piz;
    float dist = sqrtf(dx * dx + dy * dy + dz * dz + 1e-12f);

    float cx = niy * dz - niz * dy, cyv = niz * dx - nix * dz, cz = nix * dy - niy * dx;
    float y1 = sqrtf(cx * cx + cyv * cyv + cz * cz + 1e-12f);
    float x1 = nix * dx + niy * dy + niz * dz;
    float ir = __frsqrt_rn(x1 * x1 + y1 * y1);
    float s1 = y1 * ir, c1 = x1 * ir;
    cx = njy * dz - njz * dy; cyv = njz * dx - njx * dz; cz = njx * dy - njy * dx;
    float y2 = sqrtf(cx * cx + cyv * cyv + cz * cz + 1e-12f);
    float x2 = njx * dx + njy * dy + njz * dz;
    ir = __frsqrt_rn(x2 * x2 + y2 * y2);
    float s2 = y2 * ir, c2 = x2 * ir;
    cx = niy * njz - niz * njy; cyv = niz * njx - nix * njz; cz = nix * njy - niy * njx;
    float y3 = sqrtf(cx * cx + cyv * cyv + cz * cz + 1e-12f);
    float x3 = nix * njx + niy * njy + niz * njz;
    ir = __frsqrt_rn(x3 * x3 + y3 * y3);
    float s3 = y3 * ir, c3 = x3 * ir;

    float ppf[7] = { dist * invR, s1, c1, s2, c2, s3, c3 };

    int ch0 = hlf * 16;
    float h16[16];
    {
        const f16x8* xr = (const f16x8*)(xw + (size_t)j * 32 + ch0);
        f16x8 v0 = xr[0], v1 = xr[1];
        #pragma unroll
        for (int q = 0; q < 8; q++){ h16[q] = (float)v0[q]; h16[8 + q] = (float)v1[q]; }
    }
    #pragma unroll
    for (int f = 0; f < 7; f++){
        float pv = ppf[f];
        const float4* w4 = (const float4*)&w1p[f * 32 + ch0];
        #pragma unroll
        for (int q = 0; q < 4; q++){
            float4 w = w4[q];
            h16[q*4+0] = fmaf(pv, w.x, h16[q*4+0]);
            h16[q*4+1] = fmaf(pv, w.y, h16[q*4+1]);
            h16[q*4+2] = fmaf(pv, w.z, h16[q*4+2]);
            h16[q*4+3] = fmaf(pv, w.w, h16[q*4+3]);
        }
    }
    #pragma unroll
    for (int c = 0; c < 16; c++) h16[c] = tfast(h16[c]);

    {
        f16x8 c0v, c1v;
        #pragma unroll
        for (int q = 0; q < 8; q++){ c0v[q] = (_Float16)h16[q]; c1v[q] = (_Float16)h16[8 + q]; }
        int key = (e >> 1) & 3;
        int kg0 = 2 * hlf;
        *(f16x8*)&hS[e * 32 + ((kg0     ) ^ key) * 8] = c0v;
        *(f16x8*)&hS[e * 32 + ((kg0 + 1) ^ key) * 8] = c1v;
    }
    __syncthreads();

    // ---- phase B: s = h @ W2 via f16 MFMA, A-frags from precomputed W2F ----
    int lane = tid & 63, wv = tid >> 6;
    int ln15 = lane & 15, kg = lane >> 4;
    const f16x8* w2f = (const f16x8*)W2F + (size_t)cv * 512;
    f16x8 a[8];
    #pragma unroll
    for (int mt = 0; mt < 8; mt++)
        a[mt] = w2f[(mt * 4 + kg) * 16 + ln15];

    f32x4 acc[2][8];
    #pragma unroll
    for (int n = 0; n < 2; n++)
        #pragma unroll
        for (int mt = 0; mt < 8; mt++)
            acc[n][mt] = (f32x4){0.f, 0.f, 0.f, 0.f};

    #pragma unroll
    for (int nti = 0; nti < 2; nti++){
        int ee = (2 * wv + nti) * 16 + ln15;
        f16x8 b = *(const f16x8*)&hS[ee * 32 + (kg ^ ((ee >> 1) & 3)) * 8];
        #pragma unroll
        for (int mt = 0; mt < 8; mt++)
            acc[nti][mt] = __builtin_amdgcn_mfma_f32_16x16x32_f16(a[mt], b, acc[nti][mt], 0, 0, 0);
    }
    // epilogue: C layout row(ch)=mt*16+kg*4+q, col(edge)=ln15. Store into the
    // channel-permuted sLds: unit u2 = parity*16+kg*4+q holds slots mt>>1 = 0..3
    // -> pack acc[nti][{parity,parity+2,parity+4,parity+6}][q] as one b64.
    #pragma unroll
    for (int nti = 0; nti < 2; nti++){
        int ee  = (2 * wv + nti) * 16 + ln15;
        int key = ee & 15;
        #pragma unroll
        for (int parity = 0; parity < 2; parity++){
            #pragma unroll
            for (int q = 0; q < 4; q++){
                unsigned lo = pk2(acc[nti][parity + 0][q], acc[nti][parity + 2][q]);
                unsigned hi = pk2(acc[nti][parity + 4][q], acc[nti][parity + 6][q]);
                int u2 = parity * 16 + kg * 4 + q;
                ull v = ((ull)hi << 32) | lo;
                *(ull*)&sLds[ee * 128 + ((u2 ^ key) << 2)] = v;
            }
        }
    }
    __syncthreads();

    // ---- phase C: packed-f16 segmented max; thread u owns channels {u,u+32,u+64,u+96} ----
    int egp = tid >> 5;          // 0..7 edge group (16 edges)
    int u   = tid & 31;          // unit / base channel
    float b2v0 = b2[u], b2v1 = b2[u + 32], b2v2 = b2[u + 64], b2v3 = b2[u + 96];
    int curT = -1;
    f16x2 m01 = (f16x2)(_Float16)(-60000.0f), m23 = m01;
    int ebase = egp * 16;
    #pragma unroll
    for (int er = 0; er < 16; er++){
        int ee = ebase + er;
        int tg = tgtL[ee];
        ull sv = *(const ull*)&sLds[ee * 128 + ((u ^ er) << 2)];
        f16x2 s01 = __builtin_bit_cast(f16x2, (unsigned)(sv & 0xffffffffu));
        f16x2 s23 = __builtin_bit_cast(f16x2, (unsigned)(sv >> 32));
        if (tg != curT){
            if (curT >= 0){
                unsigned* fp = &feat[(size_t)curT * 384 + cv * 128 + u];
                atomicMax(fp +  0, encf((float)m01[0] + b2v0));
                atomicMax(fp + 32, encf((float)m01[1] + b2v1));
                atomicMax(fp + 64, encf((float)m23[0] + b2v2));
                atomicMax(fp + 96, encf((float)m23[1] + b2v3));
            }
            curT = tg; m01 = s01; m23 = s23;
        } else {
            m01 = __builtin_elementwise_max(m01, s01);
            m23 = __builtin_elementwise_max(m23, s23);
        }
    }
    {
        unsigned* fp = &feat[(size_t)curT * 384 + cv * 128 + u];
        atomicMax(fp +  0, encf((float)m01[0] + b2v0));
        atomicMax(fp + 32, encf((float)m01[1] + b2v1));
        atomicMax(fp + 64, encf((float)m23[0] + b2v2));
        atomicMax(fp + 96, encf((float)m23[1] + b2v3));
    }
}

// ---------- atom MLP via MFMA + residue max-pool (no atomics) ----------
__global__ __launch_bounds__(256) void k_atom(
    const unsigned* __restrict__ feat, const _Float16* __restrict__ BF,
    const float* __restrict__ ba, float* __restrict__ resm)
{
    __shared__ __align__(16) char ldsbuf[81920];
    _Float16* Ah = (_Float16*)ldsbuf;
    float*    Cs = (float*)ldsbuf;

    int tid = threadIdx.x;
    size_t base = (size_t)blockIdx.x * 80 * 384;

    #pragma unroll
    for (int itr = 0; itr < 30; itr++){
        int idx = itr * 1024 + tid * 4;
        uint4 v = *(const uint4*)&feat[base + idx];
        int r = idx / 384;
        int k = idx - r * 384;
        float f0 = tfast(decf(v.x));
        float f1 = tfast(decf(v.y));
        float f2 = tfast(decf(v.z));
        float f3 = tfast(decf(v.w));
        int u = (k >> 3) ^ (r & 7);
        *(ull*)&Ah[r * 384 + u * 8 + (k & 7)] = pk4(f0, f1, f2, f3);
    }
    __syncthreads();

    int lane = tid & 63, wv = tid >> 6;
    int ln15 = lane & 15, kg = lane >> 4;
    f32x4 acc[5][4];
    #pragma unroll
    for (int mt = 0; mt < 5; mt++)
        #pragma unroll
        for (int nti = 0; nti < 4; nti++)
            acc[mt][nti] = (f32x4){0.f, 0.f, 0.f, 0.f};

    const f16x8* bfp = (const f16x8*)BF;
    #pragma unroll
    for (int c = 0; c < 12; c++){
        f16x8 af[5];
        #pragma unroll
        for (int mt = 0; mt < 5; mt++){
            int row = mt * 16 + ln15;
            af[mt] = *(const f16x8*)&Ah[row * 384 + (((c * 4 + kg) ^ (row & 7)) << 3)];
        }
        #pragma unroll
        for (int nti = 0; nti < 4; nti++){
            f16x8 b = bfp[(((wv * 4 + nti) * 12 + c) * 4 + kg) * 16 + ln15];
            #pragma unroll
            for (int mt = 0; mt < 5; mt++)
                acc[mt][nti] = __builtin_amdgcn_mfma_f32_16x16x32_f16(af[mt], b, acc[mt][nti], 0, 0, 0);
        }
    }
    __syncthreads();

    #pragma unroll
    for (int nti = 0; nti < 4; nti++){
        int col = wv * 64 + nti * 16 + ln15;
        float bac = ba[col];
        #pragma unroll
        for (int mt = 0; mt < 5; mt++){
            #pragma unroll
            for (int q = 0; q < 4; q++){
                int row = mt * 16 + kg * 4 + q;
                Cs[row * 256 + (col ^ (kg << 2))] = acc[mt][nti][q] + bac;
            }
        }
    }
    __syncthreads();

    int res0 = blockIdx.x * 8;
    #pragma unroll
    for (int o = 0; o < 8; o++){
        int out = o * 256 + tid;
        int r = out >> 8, cc = out & 255;
        float m = -3.0e38f;
        #pragma unroll
        for (int q = 0; q < 10; q++){
            int row = r * 10 + q;
            m = fmaxf(m, Cs[row * 256 + (cc ^ (((row >> 2) & 3) << 2))]);
        }
        resm[(size_t)(res0 + r) * 256 + cc] = tfast(m);
    }
}

// ---------- res MLP + fused lw = tanh(resm@Wr+br) @ Wl ----------
__global__ __launch_bounds__(256) void k_res(
    const float* __restrict__ resm, const float* __restrict__ Wr,
    const float* __restrict__ br, const float* __restrict__ Wl,
    float* __restrict__ lw)
{
    __shared__ __align__(16) float As[16 * 16];
    __shared__ __align__(16) float Ws[16 * 512];
    __shared__ float lwL[16];
    int tid  = threadIdx.x;
    int row0 = blockIdx.x * 16;
    int colg = tid & 127, rowg = tid >> 7;
    int c0 = colg * 4;
    int lane = tid & 63;
    if (tid < 16) lwL[tid] = 0.0f;
    float4 acc[8];
    float4 brv = *(const float4*)&br[c0];
    #pragma unroll
    for (int r = 0; r < 8; r++) acc[r] = brv;

    for (int k0 = 0; k0 < 256; k0 += 16){
        __syncthreads();
        { int r = tid >> 4, k = tid & 15;
          As[tid] = resm[(size_t)(row0 + r) * 256 + k0 + k]; }
        #pragma unroll
        for (int t0 = 0; t0 < 32; t0++){
            int t = tid + t0 * 256;
            int k = t >> 9, c = t & 511;
            Ws[t] = Wr[(size_t)(k0 + k) * 512 + c];
        }
        __syncthreads();
        #pragma unroll
        for (int kk = 0; kk < 16; kk += 4){
            float4 w0 = *(const float4*)&Ws[(kk + 0) * 512 + c0];
            float4 w1 = *(const float4*)&Ws[(kk + 1) * 512 + c0];
            float4 w2 = *(const float4*)&Ws[(kk + 2) * 512 + c0];
            float4 w3 = *(const float4*)&Ws[(kk + 3) * 512 + c0];
            #pragma unroll
            for (int r = 0; r < 8; r++){
                const float4 a = *(const float4*)&As[(rowg * 8 + r) * 16 + kk];
                acc[r].x = fmaf(a.x, w0.x, fmaf(a.y, w1.x, fmaf(a.z, w2.x, fmaf(a.w, w3.x, acc[r].x))));
                acc[r].y = fmaf(a.x, w0.y, fmaf(a.y, w1.y, fmaf(a.z, w2.y, fmaf(a.w, w3.y, acc[r].y))));
                acc[r].z = fmaf(a.x, w0.z, fmaf(a.y, w1.z, fmaf(a.z, w2.z, fmaf(a.w, w3.z, acc[r].z))));
                acc[r].w = fmaf(a.x, w0.w, fmaf(a.y, w1.w, fmaf(a.z, w2.w, fmaf(a.w, w3.w, acc[r].w))));
            }
        }
    }
    float4 wl = *(const float4*)&Wl[c0];
    #pragma unroll
    for (int r = 0; r < 8; r++){
        float4 v = acc[r];
        float p = tfast(v.x) * wl.x + tfast(v.y) * wl.y + tfast(v.z) * wl.z + tfast(v.w) * wl.w;
        #pragma unroll
        for (int m = 1; m < 64; m <<= 1) p += __shfl_xor(p, m);
        if (lane == 0) atomicAdd(&lwL[rowg * 8 + r], p);
    }
    __syncthreads();
    if (tid < 16) lw[row0 + tid] = lwL[tid];
}

// ---------- final pair logits ----------
__global__ __launch_bounds__(256) void k_out(
    const float* __restrict__ lw, const int* __restrict__ src, const int* __restrict__ tgt,
    const float* __restrict__ bl, float* __restrict__ out)
{
    int p = blockIdx.x * 256 + threadIdx.x;
    if (p < PP) out[p] = lw[src[p]] - lw[tgt[p]] + bl[0];
}

extern "C" void kernel_launch(void* const* d_in, const int* in_sizes, int n_in,
                              void* d_out, int out_size, void* d_ws, size_t ws_size,
                              hipStream_t stream)
{
    const float* x    = (const float*)d_in[0];
    const float* pos  = (const float*)d_in[1];
    const float* nrm  = (const float*)d_in[2];
    const int*   ei2  = (const int*)d_in[3];
    const int*   ei3  = (const int*)d_in[4];
    const int*   ei4  = (const int*)d_in[5];
    const int*   srci = (const int*)d_in[7];
    const int*   tgti = (const int*)d_in[8];
    const float* c2W1 = (const float*)d_in[9];
    const float* c2b1 = (const float*)d_in[10];
    const float* c2W2 = (const float*)d_in[11];
    const float* c2b2 = (const float*)d_in[12];
    const float* c3W1 = (const float*)d_in[13];
    const float* c3b1 = (const float*)d_in[14];
    const float* c3W2 = (const float*)d_in[15];
    const float* c3b2 = (const float*)d_in[16];
    const float* c4W1 = (const float*)d_in[17];
    const float* c4b1 = (const float*)d_in[18];
    const float* c4W2 = (const float*)d_in[19];
    const float* c4b2 = (const float*)d_in[20];
    const float* Wa   = (const float*)d_in[21];
    const float* ba   = (const float*)d_in[22];
    const float* Wr   = (const float*)d_in[23];
    const float* br   = (const float*)d_in[24];
    const float* Wl   = (const float*)d_in[25];
    const float* bl   = (const float*)d_in[26];

    char* ws = (char*)d_ws;
    _Float16* xw1  = (_Float16*)(ws);                 // 19,200,000 B
    _Float16* W2F  = (_Float16*)(ws +  19200000);     //     24,576 B
    _Float16* BF   = (_Float16*)(ws +  19224576);     //    196,608 B
    unsigned* cur  = (unsigned*)(ws +  19421184);     //  1,200,000 B
    ull*      esort= (ull*)     (ws +  20621312);     // 24,000,000 B
    unsigned* feat = (unsigned*)(ws +  44621312);     // 153,600,000 B
    float*    resm = (float*)   (ws + 198221312);     // 10,240,000 B
    float*    lw   = (float*)   (ws + 208461312);     // 40,000 B

    hipMemsetAsync(cur,  0, (size_t)3 * NN * 4, stream);
    hipMemsetAsync(feat, 0, (size_t)NN * 384 * 4, stream);

    k_xw1<<<9375, 256, 0, stream>>>(x, c2W1, c2b1, c3W1, c3b1, c4W1, c4b1, xw1);
    k_prep<<<96, 256, 0, stream>>>(Wa, BF);
    k_prepw<<<6, 256, 0, stream>>>(c2W2, c3W2, c4W2, W2F);
    k_hist<<<(3 * EE + 255) / 256, 256, 0, stream>>>(ei2, ei3, ei4, cur);
    k_scan<<<3, 1024, 0, stream>>>(cur);
    k_scatter<<<(3 * EE + 255) / 256, 256, 0, stream>>>(ei2, ei3, ei4, cur, esort);
    dim3 gconv((EE + 127) / 128, 3);
    k_conv<<<gconv, 256, 0, stream>>>(esort, xw1, pos, nrm,
                                      c2W1, c3W1, c4W1, W2F,
                                      c2b2, c3b2, c4b2, feat);
    k_atom<<<NN / 80, 256, 0, stream>>>(feat, BF, ba, resm);
    k_res<<<RR / 16, 256, 0, stream>>>(resm, Wr, br, Wl, lw);
    k_out<<<(PP + 255) / 256, 256, 0, stream>>>(lw, srci, tgti, bl, (float*)d_out);
}

// Round 10
// 873.009 us; speedup vs baseline: 1.5503x; 1.0893x over previous
//
#include <hip/hip_runtime.h>
#include <hip/hip_bf16.h>

#define NN 100000
#define EE 1000000
#define RR 10000
#define PP 50000

typedef _Float16 f16x8 __attribute__((ext_vector_type(8)));
typedef _Float16 f16x2 __attribute__((ext_vector_type(2)));
typedef float f32x4 __attribute__((ext_vector_type(4)));
typedef unsigned long long ull;

// ---------- helpers ----------
__device__ __forceinline__ float tfast(float x){
    float e = __expf(2.0f * x);
    return 1.0f - __fdividef(2.0f, e + 1.0f);
}
__device__ __forceinline__ unsigned encf(float f){
    unsigned u = __float_as_uint(f);
    return (u & 0x80000000u) ? ~u : (u | 0x80000000u);
}
__device__ __forceinline__ float decf(unsigned u){
    return (u & 0x80000000u) ? __uint_as_float(u ^ 0x80000000u) : __uint_as_float(~u);
}
__device__ __forceinline__ unsigned pk2(float a, float b){
    _Float16 ha = (_Float16)a, hb = (_Float16)b;
    unsigned short ua = __builtin_bit_cast(unsigned short, ha);
    unsigned short ub = __builtin_bit_cast(unsigned short, hb);
    return (unsigned)ua | ((unsigned)ub << 16);
}
__device__ __forceinline__ ull pk4(float a, float b, float c, float d){
    return ((ull)pk2(c, d) << 32) | (ull)pk2(a, b);
}

// ---------- fused pre-pass: xw1 | Wa-prep | W2-prep | hist(4 edges/thr) | feat zero ----------
// block ranges: [0,9375) xw1, [9375,9471) prep, [9471,9477) prepw,
//               [9477,12407) hist, [12407,21782) feat-zero
__global__ __launch_bounds__(256) void k_pre(
    const float* __restrict__ x,
    const float* __restrict__ W1_0, const float* __restrict__ b1_0,
    const float* __restrict__ W1_1, const float* __restrict__ b1_1,
    const float* __restrict__ W1_2, const float* __restrict__ b1_2,
    _Float16* __restrict__ xw1,
    const float* __restrict__ Wa, _Float16* __restrict__ BF,
    const float* __restrict__ W2_0, const float* __restrict__ W2_1, const float* __restrict__ W2_2,
    _Float16* __restrict__ W2F,
    const int* __restrict__ e2, const int* __restrict__ e3, const int* __restrict__ e4,
    unsigned* __restrict__ cur,
    uint4* __restrict__ featz)
{
    int b = blockIdx.x, tid = threadIdx.x;
    if (b < 9375){
        // ---- xw1 = x @ W1[0:25,:] + b1, stored f16 ----
        int g = b * 256 + tid;                       // 2.4M exactly
        int cv  = g / (NN * 8);
        int rem = g - cv * (NN * 8);
        int n   = rem >> 3, cg = rem & 7;
        const float* W1 = (cv == 0) ? W1_0 : ((cv == 1) ? W1_1 : W1_2);
        const float* b1 = (cv == 0) ? b1_0 : ((cv == 1) ? b1_1 : b1_2);
        float4 acc = *(const float4*)&b1[cg * 4];
        const float* xr = x + (size_t)n * 25;
        #pragma unroll
        for (int m = 0; m < 25; m++){
            float xv = xr[m];
            float4 w = *(const float4*)&W1[m * 32 + cg * 4];
            acc.x = fmaf(xv, w.x, acc.x); acc.y = fmaf(xv, w.y, acc.y);
            acc.z = fmaf(xv, w.z, acc.z); acc.w = fmaf(xv, w.w, acc.w);
        }
        *(ull*)&xw1[((size_t)cv * NN + n) * 32 + cg * 4] = pk4(acc.x, acc.y, acc.z, acc.w);
    } else if (b < 9471){
        // ---- Wa -> fragment-linear f16 table BF ----
        int g = (b - 9375) * 256 + tid;              // 24576 exactly
        int o = g * 4;
        int j0 = o & 7;
        int t1 = o >> 3;
        int ln = t1 & 15;
        int t2 = t1 >> 4;
        int kg = t2 & 3;
        int t3 = t2 >> 2;
        int c  = t3 % 12;
        int nt = t3 / 12;
        int colg = nt * 16 + ln;
        int krow = c * 32 + kg * 8 + j0;
        float w0 = Wa[(size_t)(krow + 0) * 256 + colg];
        float w1 = Wa[(size_t)(krow + 1) * 256 + colg];
        float w2 = Wa[(size_t)(krow + 2) * 256 + colg];
        float w3 = Wa[(size_t)(krow + 3) * 256 + colg];
        *(ull*)&BF[o] = pk4(w0, w1, w2, w3);
    } else if (b < 9477){
        // ---- W2 -> fragment-linear f16 tables ----
        int g = (b - 9471) * 256 + tid;              // 1536 exactly
        int cv = g >> 9;
        int f  = g & 511;
        int ln = f & 15;
        int kg = (f >> 4) & 3;
        int mt = f >> 6;
        const float* W2 = (cv == 0) ? W2_0 : ((cv == 1) ? W2_1 : W2_2);
        f16x8 v;
        #pragma unroll
        for (int jj = 0; jj < 8; jj++)
            v[jj] = (_Float16)W2[(kg * 8 + jj) * 128 + mt * 16 + ln];
        ((f16x8*)W2F)[g] = v;
    } else if (b < 12407){
        // ---- histogram of edge targets, 4 edges/thread ----
        int t4 = (b - 9477) * 256 + tid;
        if (t4 < 750000){
            long ge = (long)t4 * 4;
            int cv = (int)(ge / EE);
            int e  = (int)(ge - (long)cv * EE);
            const int* ei = (cv == 0) ? e2 : ((cv == 1) ? e3 : e4);
            uint4 ts = *(const uint4*)&ei[EE + e];   // EE%4==0: pack never crosses conv
            unsigned* cc = cur + (size_t)cv * NN;
            atomicAdd(&cc[ts.x], 1u);
            atomicAdd(&cc[ts.y], 1u);
            atomicAdd(&cc[ts.z], 1u);
            atomicAdd(&cc[ts.w], 1u);
        }
    } else {
        // ---- feat zero: 9375 blocks x 1024 uint4 = 38.4M words exactly ----
        size_t base = (size_t)(b - 12407) * 1024;
        uint4 z = make_uint4(0u, 0u, 0u, 0u);
        #pragma unroll
        for (int k = 0; k < 4; k++)
            featz[base + k * 256 + tid] = z;
    }
}

// ---------- scan stage A: per-1024-chunk exclusive scan + chunk totals (294 blocks) ----------
__global__ __launch_bounds__(1024) void k_scanA(unsigned* __restrict__ cur, unsigned* __restrict__ totals)
{
    int c = blockIdx.x;
    int cv = c / 98, lc = c - cv * 98;
    unsigned* a = cur + (size_t)cv * NN;
    __shared__ unsigned wsum[16];
    int tid = threadIdx.x, lane = tid & 63, wv = tid >> 6;
    int idx = lc * 1024 + tid;
    unsigned v = (idx < NN) ? a[idx] : 0u;
    unsigned s = v;
    #pragma unroll
    for (int d = 1; d < 64; d <<= 1){
        unsigned t = (unsigned)__shfl_up((int)s, d);
        if (lane >= d) s += t;
    }
    if (lane == 63) wsum[wv] = s;
    __syncthreads();
    if (wv == 0 && lane < 16){
        unsigned t = wsum[lane];
        #pragma unroll
        for (int d = 1; d < 16; d <<= 1){
            unsigned u = (unsigned)__shfl_up((int)t, d);
            if (lane >= d) t += u;
        }
        wsum[lane] = t;
    }
    __syncthreads();
    unsigned waveoff = (wv == 0) ? 0u : wsum[wv - 1];
    if (idx < NN) a[idx] = waveoff + s - v;          // exclusive within chunk
    if (tid == 0) totals[c] = wsum[15];              // chunk total
}

// ---------- scan stage B: segmented exclusive scan of 294 chunk totals (3 segs of 98) ----------
__global__ __launch_bounds__(512) void k_scanB(unsigned* __restrict__ totals)
{
    __shared__ unsigned buf[294];
    int tid = threadIdx.x;
    unsigned own = 0;
    if (tid < 294){ own = totals[tid]; buf[tid] = own; }
    __syncthreads();
    for (int d = 1; d < 98; d <<= 1){
        unsigned add = 0;
        if (tid < 294 && (tid % 98) >= d) add = buf[tid - d];
        __syncthreads();
        if (tid < 294) buf[tid] += add;
        __syncthreads();
    }
    if (tid < 294) totals[tid] = buf[tid] - own;     // exclusive within segment
}

// ---------- scatter edges into target-sorted order, 4 edges/thread ----------
__global__ __launch_bounds__(256) void k_scatter(
    const int* __restrict__ e2, const int* __restrict__ e3, const int* __restrict__ e4,
    unsigned* __restrict__ cur, const unsigned* __restrict__ totals, ull* __restrict__ esort)
{
    int t4 = blockIdx.x * 256 + threadIdx.x;
    if (t4 >= 750000) return;
    long ge = (long)t4 * 4;
    int cv = (int)(ge / EE);
    int e  = (int)(ge - (long)cv * EE);
    const int* ei = (cv == 0) ? e2 : ((cv == 1) ? e3 : e4);
    uint4 js = *(const uint4*)&ei[e];
    uint4 ts = *(const uint4*)&ei[EE + e];
    unsigned* cc = cur + (size_t)cv * NN;
    const unsigned* tc = totals + cv * 98;
    ull* es = esort + (size_t)cv * EE;
    {
        unsigned p = atomicAdd(&cc[ts.x], 1u) + tc[ts.x >> 10];
        es[p] = ((ull)ts.x << 32) | js.x;
    }
    {
        unsigned p = atomicAdd(&cc[ts.y], 1u) + tc[ts.y >> 10];
        es[p] = ((ull)ts.y << 32) | js.y;
    }
    {
        unsigned p = atomicAdd(&cc[ts.z], 1u) + tc[ts.z >> 10];
        es[p] = ((ull)ts.z << 32) | js.z;
    }
    {
        unsigned p = atomicAdd(&cc[ts.w], 1u) + tc[ts.w >> 10];
        es[p] = ((ull)ts.w << 32) | js.w;
    }
}

// ---------- fused PPF conv (FROZEN from round 9) ----------
// sLds channel permutation: 8B unit u (u=0..31) holds channels {u, u+32, u+64, u+96}.
// Phase-C thread u owns those 4 channels; flush instruction k writes feat word k*32+u
// -> 32 lanes contiguous 128B per atomic instruction (coalesced).
__global__ __launch_bounds__(256) void k_conv(
    const ull* __restrict__ esort,
    const _Float16* __restrict__ xw1,
    const float* __restrict__ pos, const float* __restrict__ nrm,
    const float* __restrict__ W1_0, const float* __restrict__ W1_1, const float* __restrict__ W1_2,
    const _Float16* __restrict__ W2F,
    const float* __restrict__ b2_0, const float* __restrict__ b2_1, const float* __restrict__ b2_2,
    unsigned* __restrict__ feat)
{
    const int cv = blockIdx.y;
    const float invR = (cv == 0) ? 0.2f : ((cv == 1) ? (1.0f / 8.5f) : 0.1f);
    const float* W1 = (cv == 0) ? W1_0 : ((cv == 1) ? W1_1 : W1_2);
    const float* b2 = (cv == 0) ? b2_0 : ((cv == 1) ? b2_1 : b2_2);
    const ull* eS = esort + (size_t)cv * EE;
    const _Float16* xw = xw1 + (size_t)cv * NN * 32;

    __shared__ __align__(16) _Float16 hS[128 * 32];
    __shared__ __align__(16) _Float16 sLds[128 * 128];
    __shared__ float w1p[224];
    __shared__ int tgtL[128];

    int tid = threadIdx.x;
    if (tid < 224) w1p[tid] = W1[800 + tid];

    int gbase = blockIdx.x * 128;
    int e     = tid & 127;
    int hlf   = tid >> 7;
    int eg = gbase + e; if (eg >= EE) eg = EE - 1;   // dup last edge: max-idempotent
    ull ev = eS[eg];
    int j  = (int)(unsigned)(ev & 0xffffffffu);
    int it = (int)(unsigned)(ev >> 32);
    if (hlf == 0) tgtL[e] = it;
    __syncthreads();

    float pix = pos[(size_t)it * 3 + 0], piy = pos[(size_t)it * 3 + 1], piz = pos[(size_t)it * 3 + 2];
    float pjx = pos[(size_t)j  * 3 + 0], pjy = pos[(size_t)j  * 3 + 1], pjz = pos[(size_t)j  * 3 + 2];
    float nix = nrm[(size_t)it * 3 + 0], niy = nrm[(size_t)it * 3 + 1], niz = nrm[(size_t)it * 3 + 2];
    float njx = nrm[(size_t)j  * 3 + 0], njy = nrm[(size_t)j  * 3 + 1], njz = nrm[(size_t)j  * 3 + 2];

    float dx = pjx - pix, dy = pjy - piy, dz = pjz - piz;
    float dist = sqrtf(dx * dx + dy * dy + dz * dz + 1e-12f);

    float cx = niy * dz - niz * dy, cyv = niz * dx - nix * dz, cz = nix * dy - niy * dx;
    float y1 = sqrtf(cx * cx + cyv * cyv + cz * cz + 1e-12f);
    float x1 = nix * dx + niy * dy + niz * dz;
    float ir = __frsqrt_rn(x1 * x1 + y1 * y1);
    float s1 = y1 * ir, c1 = x1 * ir;
    cx = njy * dz - njz * dy; cyv = njz * dx - njx * dz; cz = njx * dy - njy * dx;
    float y2 = sqrtf(cx * cx + cyv * cyv + cz * cz + 1e-12f);
    float x2 = njx * dx + njy * dy + njz * dz;
    ir = __frsqrt_rn(x2 * x2 + y2 * y2);
    float s2 = y2 * ir, c2 = x2 * ir;
    cx = niy * njz - niz * njy; cyv = niz * njx - nix * njz; cz = nix * njy - niy * njx;
    float y3 = sqrtf(cx * cx + cyv * cyv + cz * cz + 1e-12f);
    float x3 = nix * njx + niy * njy + niz * njz;
    ir = __frsqrt_rn(x3 * x3 + y3 * y3);
    float s3 = y3 * ir, c3 = x3 * ir;

    float ppf[7] = { dist * invR, s1, c1, s2, c2, s3, c3 };

    int ch0 = hlf * 16;
    float h16[16];
    {
        const f16x8* xr = (const f16x8*)(xw + (size_t)j * 32 + ch0);
        f16x8 v0 = xr[0], v1 = xr[1];
        #pragma unroll
        for (int q = 0; q < 8; q++){ h16[q] = (float)v0[q]; h16[8 + q] = (float)v1[q]; }
    }
    #pragma unroll
    for (int f = 0; f < 7; f++){
        float pv = ppf[f];
        const float4* w4 = (const float4*)&w1p[f * 32 + ch0];
        #pragma unroll
        for (int q = 0; q < 4; q++){
            float4 w = w4[q];
            h16[q*4+0] = fmaf(pv, w.x, h16[q*4+0]);
            h16[q*4+1] = fmaf(pv, w.y, h16[q*4+1]);
            h16[q*4+2] = fmaf(pv, w.z, h16[q*4+2]);
            h16[q*4+3] = fmaf(pv, w.w, h16[q*4+3]);
        }
    }
    #pragma unroll
    for (int c = 0; c < 16; c++) h16[c] = tfast(h16[c]);

    {
        f16x8 c0v, c1v;
        #pragma unroll
        for (int q = 0; q < 8; q++){ c0v[q] = (_Float16)h16[q]; c1v[q] = (_Float16)h16[8 + q]; }
        int key = (e >> 1) & 3;
        int kg0 = 2 * hlf;
        *(f16x8*)&hS[e * 32 + ((kg0     ) ^ key) * 8] = c0v;
        *(f16x8*)&hS[e * 32 + ((kg0 + 1) ^ key) * 8] = c1v;
    }
    __syncthreads();

    // ---- phase B: s = h @ W2 via f16 MFMA ----
    int lane = tid & 63, wv = tid >> 6;
    int ln15 = lane & 15, kg = lane >> 4;
    const f16x8* w2f = (const f16x8*)W2F + (size_t)cv * 512;
    f16x8 a[8];
    #pragma unroll
    for (int mt = 0; mt < 8; mt++)
        a[mt] = w2f[(mt * 4 + kg) * 16 + ln15];

    f32x4 acc[2][8];
    #pragma unroll
    for (int n = 0; n < 2; n++)
        #pragma unroll
        for (int mt = 0; mt < 8; mt++)
            acc[n][mt] = (f32x4){0.f, 0.f, 0.f, 0.f};

    #pragma unroll
    for (int nti = 0; nti < 2; nti++){
        int ee = (2 * wv + nti) * 16 + ln15;
        f16x8 b = *(const f16x8*)&hS[ee * 32 + (kg ^ ((ee >> 1) & 3)) * 8];
        #pragma unroll
        for (int mt = 0; mt < 8; mt++)
            acc[nti][mt] = __builtin_amdgcn_mfma_f32_16x16x32_f16(a[mt], b, acc[nti][mt], 0, 0, 0);
    }
    #pragma unroll
    for (int nti = 0; nti < 2; nti++){
        int ee  = (2 * wv + nti) * 16 + ln15;
        int key = ee & 15;
        #pragma unroll
        for (int parity = 0; parity < 2; parity++){
            #pragma unroll
            for (int q = 0; q < 4; q++){
                unsigned lo = pk2(acc[nti][parity + 0][q], acc[nti][parity + 2][q]);
                unsigned hi = pk2(acc[nti][parity + 4][q], acc[nti][parity + 6][q]);
                int u2 = parity * 16 + kg * 4 + q;
                ull v = ((ull)hi << 32) | lo;
                *(ull*)&sLds[ee * 128 + ((u2 ^ key) << 2)] = v;
            }
        }
    }
    __syncthreads();

    // ---- phase C: packed-f16 segmented max; thread u owns channels {u,u+32,u+64,u+96} ----
    int egp = tid >> 5;
    int u   = tid & 31;
    float b2v0 = b2[u], b2v1 = b2[u + 32], b2v2 = b2[u + 64], b2v3 = b2[u + 96];
    int curT = -1;
    f16x2 m01 = (f16x2)(_Float16)(-60000.0f), m23 = m01;
    int ebase = egp * 16;
    #pragma unroll
    for (int er = 0; er < 16; er++){
        int ee = ebase + er;
        int tg = tgtL[ee];
        ull sv = *(const ull*)&sLds[ee * 128 + ((u ^ er) << 2)];
        f16x2 s01 = __builtin_bit_cast(f16x2, (unsigned)(sv & 0xffffffffu));
        f16x2 s23 = __builtin_bit_cast(f16x2, (unsigned)(sv >> 32));
        if (tg != curT){
            if (curT >= 0){
                unsigned* fp = &feat[(size_t)curT * 384 + cv * 128 + u];
                atomicMax(fp +  0, encf((float)m01[0] + b2v0));
                atomicMax(fp + 32, encf((float)m01[1] + b2v1));
                atomicMax(fp + 64, encf((float)m23[0] + b2v2));
                atomicMax(fp + 96, encf((float)m23[1] + b2v3));
            }
            curT = tg; m01 = s01; m23 = s23;
        } else {
            m01 = __builtin_elementwise_max(m01, s01);
            m23 = __builtin_elementwise_max(m23, s23);
        }
    }
    {
        unsigned* fp = &feat[(size_t)curT * 384 + cv * 128 + u];
        atomicMax(fp +  0, encf((float)m01[0] + b2v0));
        atomicMax(fp + 32, encf((float)m01[1] + b2v1));
        atomicMax(fp + 64, encf((float)m23[0] + b2v2));
        atomicMax(fp + 96, encf((float)m23[1] + b2v3));
    }
}

// ---------- atom MLP via MFMA + residue max-pool (no atomics) ----------
__global__ __launch_bounds__(256) void k_atom(
    const unsigned* __restrict__ feat, const _Float16* __restrict__ BF,
    const float* __restrict__ ba, float* __restrict__ resm)
{
    __shared__ __align__(16) char ldsbuf[81920];
    _Float16* Ah = (_Float16*)ldsbuf;
    float*    Cs = (float*)ldsbuf;

    int tid = threadIdx.x;
    size_t base = (size_t)blockIdx.x * 80 * 384;

    #pragma unroll
    for (int itr = 0; itr < 30; itr++){
        int idx = itr * 1024 + tid * 4;
        uint4 v = *(const uint4*)&feat[base + idx];
        int r = idx / 384;
        int k = idx - r * 384;
        float f0 = tfast(decf(v.x));
        float f1 = tfast(decf(v.y));
        float f2 = tfast(decf(v.z));
        float f3 = tfast(decf(v.w));
        int u = (k >> 3) ^ (r & 7);
        *(ull*)&Ah[r * 384 + u * 8 + (k & 7)] = pk4(f0, f1, f2, f3);
    }
    __syncthreads();

    int lane = tid & 63, wv = tid >> 6;
    int ln15 = lane & 15, kg = lane >> 4;
    f32x4 acc[5][4];
    #pragma unroll
    for (int mt = 0; mt < 5; mt++)
        #pragma unroll
        for (int nti = 0; nti < 4; nti++)
            acc[mt][nti] = (f32x4){0.f, 0.f, 0.f, 0.f};

    const f16x8* bfp = (const f16x8*)BF;
    #pragma unroll
    for (int c = 0; c < 12; c++){
        f16x8 af[5];
        #pragma unroll
        for (int mt = 0; mt < 5; mt++){
            int row = mt * 16 + ln15;
            af[mt] = *(const f16x8*)&Ah[row * 384 + (((c * 4 + kg) ^ (row & 7)) << 3)];
        }
        #pragma unroll
        for (int nti = 0; nti < 4; nti++){
            f16x8 b = bfp[(((wv * 4 + nti) * 12 + c) * 4 + kg) * 16 + ln15];
            #pragma unroll
            for (int mt = 0; mt < 5; mt++)
                acc[mt][nti] = __builtin_amdgcn_mfma_f32_16x16x32_f16(af[mt], b, acc[mt][nti], 0, 0, 0);
        }
    }
    __syncthreads();

    #pragma unroll
    for (int nti = 0; nti < 4; nti++){
        int col = wv * 64 + nti * 16 + ln15;
        float bac = ba[col];
        #pragma unroll
        for (int mt = 0; mt < 5; mt++){
            #pragma unroll
            for (int q = 0; q < 4; q++){
                int row = mt * 16 + kg * 4 + q;
                Cs[row * 256 + (col ^ (kg << 2))] = acc[mt][nti][q] + bac;
            }
        }
    }
    __syncthreads();

    int res0 = blockIdx.x * 8;
    #pragma unroll
    for (int o = 0; o < 8; o++){
        int out = o * 256 + tid;
        int r = out >> 8, cc = out & 255;
        float m = -3.0e38f;
        #pragma unroll
        for (int q = 0; q < 10; q++){
            int row = r * 10 + q;
            m = fmaxf(m, Cs[row * 256 + (cc ^ (((row >> 2) & 3) << 2))]);
        }
        resm[(size_t)(res0 + r) * 256 + cc] = tfast(m);
    }
}

// ---------- res MLP + fused lw = tanh(resm@Wr+br) @ Wl ----------
__global__ __launch_bounds__(256) void k_res(
    const float* __restrict__ resm, const float* __restrict__ Wr,
    const float* __restrict__ br, const float* __restrict__ Wl,
    float* __restrict__ lw)
{
    __shared__ __align__(16) float As[16 * 16];
    __shared__ __align__(16) float Ws[16 * 512];
    __shared__ float lwL[16];
    int tid  = threadIdx.x;
    int row0 = blockIdx.x * 16;
    int colg = tid & 127, rowg = tid >> 7;
    int c0 = colg * 4;
    int lane = tid & 63;
    if (tid < 16) lwL[tid] = 0.0f;
    float4 acc[8];
    float4 brv = *(const float4*)&br[c0];
    #pragma unroll
    for (int r = 0; r < 8; r++) acc[r] = brv;

    for (int k0 = 0; k0 < 256; k0 += 16){
        __syncthreads();
        { int r = tid >> 4, k = tid & 15;
          As[tid] = resm[(size_t)(row0 + r) * 256 + k0 + k]; }
        #pragma unroll
        for (int t0 = 0; t0 < 32; t0++){
            int t = tid + t0 * 256;
            int k = t >> 9, c = t & 511;
            Ws[t] = Wr[(size_t)(k0 + k) * 512 + c];
        }
        __syncthreads();
        #pragma unroll
        for (int kk = 0; kk < 16; kk += 4){
            float4 w0 = *(const float4*)&Ws[(kk + 0) * 512 + c0];
            float4 w1 = *(const float4*)&Ws[(kk + 1) * 512 + c0];
            float4 w2 = *(const float4*)&Ws[(kk + 2) * 512 + c0];
            float4 w3 = *(const float4*)&Ws[(kk + 3) * 512 + c0];
            #pragma unroll
            for (int r = 0; r < 8; r++){
                const float4 a = *(const float4*)&As[(rowg * 8 + r) * 16 + kk];
                acc[r].x = fmaf(a.x, w0.x, fmaf(a.y, w1.x, fmaf(a.z, w2.x, fmaf(a.w, w3.x, acc[r].x))));
                acc[r].y = fmaf(a.x, w0.y, fmaf(a.y, w1.y, fmaf(a.z, w2.y, fmaf(a.w, w3.y, acc[r].y))));
                acc[r].z = fmaf(a.x, w0.z, fmaf(a.y, w1.z, fmaf(a.z, w2.z, fmaf(a.w, w3.z, acc[r].z))));
                acc[r].w = fmaf(a.x, w0.w, fmaf(a.y, w1.w, fmaf(a.z, w2.w, fmaf(a.w, w3.w, acc[r].w))));
            }
        }
    }
    float4 wl = *(const float4*)&Wl[c0];
    #pragma unroll
    for (int r = 0; r < 8; r++){
        float4 v = acc[r];
        float p = tfast(v.x) * wl.x + tfast(v.y) * wl.y + tfast(v.z) * wl.z + tfast(v.w) * wl.w;
        #pragma unroll
        for (int m = 1; m < 64; m <<= 1) p += __shfl_xor(p, m);
        if (lane == 0) atomicAdd(&lwL[rowg * 8 + r], p);
    }
    __syncthreads();
    if (tid < 16) lw[row0 + tid] = lwL[tid];
}

// ---------- final pair logits ----------
__global__ __launch_bounds__(256) void k_out(
    const float* __restrict__ lw, const int* __restrict__ src, const int* __restrict__ tgt,
    const float* __restrict__ bl, float* __restrict__ out)
{
    int p = blockIdx.x * 256 + threadIdx.x;
    if (p < PP) out[p] = lw[src[p]] - lw[tgt[p]] + bl[0];
}

extern "C" void kernel_launch(void* const* d_in, const int* in_sizes, int n_in,
                              void* d_out, int out_size, void* d_ws, size_t ws_size,
                              hipStream_t stream)
{
    const float* x    = (const float*)d_in[0];
    const float* pos  = (const float*)d_in[1];
    const float* nrm  = (const float*)d_in[2];
    const int*   ei2  = (const int*)d_in[3];
    const int*   ei3  = (const int*)d_in[4];
    const int*   ei4  = (const int*)d_in[5];
    const int*   srci = (const int*)d_in[7];
    const int*   tgti = (const int*)d_in[8];
    const float* c2W1 = (const float*)d_in[9];
    const float* c2b1 = (const float*)d_in[10];
    const float* c2W2 = (const float*)d_in[11];
    const float* c2b2 = (const float*)d_in[12];
    const float* c3W1 = (const float*)d_in[13];
    const float* c3b1 = (const float*)d_in[14];
    const float* c3W2 = (const float*)d_in[15];
    const float* c3b2 = (const float*)d_in[16];
    const float* c4W1 = (const float*)d_in[17];
    const float* c4b1 = (const float*)d_in[18];
    const float* c4W2 = (const float*)d_in[19];
    const float* c4b2 = (const float*)d_in[20];
    const float* Wa   = (const float*)d_in[21];
    const float* ba   = (const float*)d_in[22];
    const float* Wr   = (const float*)d_in[23];
    const float* br   = (const float*)d_in[24];
    const float* Wl   = (const float*)d_in[25];
    const float* bl   = (const float*)d_in[26];

    char* ws = (char*)d_ws;
    _Float16* xw1   = (_Float16*)(ws);                 // 19,200,000 B
    _Float16* W2F   = (_Float16*)(ws +  19200000);     //     24,576 B
    _Float16* BF    = (_Float16*)(ws +  19224576);     //    196,608 B
    unsigned* cur   = (unsigned*)(ws +  19421184);     //  1,200,000 B
    ull*      esort = (ull*)     (ws +  20621312);     // 24,000,000 B
    unsigned* feat  = (unsigned*)(ws +  44621312);     // 153,600,000 B
    float*    resm  = (float*)   (ws + 198221312);     // 10,240,000 B
    float*    lw    = (float*)   (ws + 208461312);     // 40,000 B
    unsigned* totals= (unsigned*)(ws + 208501312);     // 2,048 B

    hipMemsetAsync(cur, 0, (size_t)3 * NN * 4, stream);

    k_pre<<<21782, 256, 0, stream>>>(x, c2W1, c2b1, c3W1, c3b1, c4W1, c4b1, xw1,
                                     Wa, BF, c2W2, c3W2, c4W2, W2F,
                                     ei2, ei3, ei4, cur, (uint4*)feat);
    k_scanA<<<294, 1024, 0, stream>>>(cur, totals);
    k_scanB<<<1, 512, 0, stream>>>(totals);
    k_scatter<<<2930, 256, 0, stream>>>(ei2, ei3, ei4, cur, totals, esort);
    dim3 gconv((EE + 127) / 128, 3);
    k_conv<<<gconv, 256, 0, stream>>>(esort, xw1, pos, nrm,
                                      c2W1, c3W1, c4W1, W2F,
                                      c2b2, c3b2, c4b2, feat);
    k_atom<<<NN / 80, 256, 0, stream>>>(feat, BF, ba, resm);
    k_res<<<RR / 16, 256, 0, stream>>>(resm, Wr, br, Wl, lw);
    k_out<<<(PP + 255) / 256, 256, 0, stream>>>(lw, srci, tgti, bl, (float*)d_out);
}